// Round 3
// baseline (359.448 us; speedup 1.0000x reference)
//
#include <hip/hip_runtime.h>
#include <hip/hip_fp16.h>
#include <float.h>

#define C_DEPTH 128
#define H_DIM 128
#define W_DIM 128
#define NPIX (H_DIM * W_DIM)
#define N_SAMP 32
#define N_FINAL 8
#define N_LINES 50000

typedef float v4f __attribute__((ext_vector_type(4)));

// ---------------------------------------------------------------------------
// Pre-pass: transpose features (C,H,W) fp32 -> (H*W, C) fp16.
// Pad 130 (even) so the read-back can be float2; stores are half2 (4 B/lane,
// full-width 256 B wave stores).
// ---------------------------------------------------------------------------
__global__ __launch_bounds__(256) void transpose_chw_hwc(
    const float* __restrict__ in, __half* __restrict__ out) {
    __shared__ float tile[64 * 130];
    const int p0 = blockIdx.x * 64;
    const int t = threadIdx.x;

    const int p_local = t & 63;
    const int cg = t >> 6;  // 0..3, each covers 32 channels
    #pragma unroll
    for (int i = 0; i < 32; ++i) {
        const int ch = cg * 32 + i;
        tile[p_local * 130 + ch] = in[ch * NPIX + p0 + p_local];
    }
    __syncthreads();

    const int cp = (t & 63) * 2;  // channel pair 0,2,...,126
    const int pg = t >> 6;        // 0..3, each covers 16 pixels
    #pragma unroll
    for (int i = 0; i < 16; ++i) {
        const int p = pg * 16 + i;
        const float2 f2 = *reinterpret_cast<const float2*>(&tile[p * 130 + cp]);
        *reinterpret_cast<__half2*>(&out[(size_t)(p0 + p) * C_DEPTH + cp]) =
            __floats2half2_rn(f2.x, f2.y);
    }
}

// ---------------------------------------------------------------------------
// Main kernel: 1 block = 1 line, 128 threads = 8 pool-groups x 16 ch-groups.
//   f  = t >> 4 : pool group, consumes samples 4f..4f+3 (exact pool window)
//   tg = t & 15 : channel group, owns channels 8*tg .. 8*tg+7
// Coords/weights computed once by 32 threads into LDS (cheap, amortized —
// per-thread recompute cost +25us in round-2 experiment).
// All 16 gather loads issued upfront as NONTEMPORAL (no L1 allocate): the
// gather working set is 6.4 MB/CU vs 32 KB L1 — pure thrash; bypassing L1
// targets the miss-queue depth that caps effective L2 gather bandwidth.
// ---------------------------------------------------------------------------
__global__ __launch_bounds__(128) void line_pool(
    const __half* __restrict__ ft,      // (H*W, C) fp16 transposed features
    const float* __restrict__ lines,    // (N_LINES, 4)
    float* __restrict__ out) {
    __shared__ int4   s_off[N_SAMP];    // corner offsets in elements (x C)
    __shared__ float4 s_w[N_SAMP];      // bilinear weights (w00,w10,w01,w11)
    __shared__ float  o_tile[C_DEPTH * 9];

    const int line = blockIdx.x;
    const int t = threadIdx.x;

    if (t < N_SAMP) {
        const float4 l = reinterpret_cast<const float4*>(lines)[line];
        const float ts = (float)t / 31.0f;  // exact 1.0 at t=31
        const float px = l.x * ts + l.z * (1.0f - ts) - 0.5f;
        const float py = l.y * ts + l.w * (1.0f - ts) - 0.5f;
        // Reference: clamp AFTER floor, weights from the CLAMPED float coords.
        const float px0 = fminf(fmaxf(floorf(px), 0.0f), (float)(W_DIM - 1));
        const float py0 = fminf(fmaxf(floorf(py), 0.0f), (float)(H_DIM - 1));
        const float px1 = fminf(px0 + 1.0f, (float)(W_DIM - 1));
        const float py1 = fminf(py0 + 1.0f, (float)(H_DIM - 1));
        const int ix0 = (int)px0, iy0 = (int)py0;
        const int ix1 = (int)px1, iy1 = (int)py1;
        const float wx0 = px1 - px, wx1 = px - px0;
        const float wy0 = py1 - py, wy1 = py - py0;
        s_off[t] = make_int4((iy0 * W_DIM + ix0) * C_DEPTH,
                             (iy1 * W_DIM + ix0) * C_DEPTH,
                             (iy0 * W_DIM + ix1) * C_DEPTH,
                             (iy1 * W_DIM + ix1) * C_DEPTH);
        s_w[t] = make_float4(wy0 * wx0, wy1 * wx0, wy0 * wx1, wy1 * wx1);
    }
    __syncthreads();

    const int f  = t >> 4;
    const int tg = t & 15;
    const int c0 = tg * 8;

    // Issue all 16 gathers back-to-back, nontemporal (bypass L1 allocate).
    v4f r[16];
    #pragma unroll
    for (int si = 0; si < 4; ++si) {
        const int4 o = s_off[f * 4 + si];
        r[si * 4 + 0] = __builtin_nontemporal_load(
            reinterpret_cast<const v4f*>(ft + o.x + c0));
        r[si * 4 + 1] = __builtin_nontemporal_load(
            reinterpret_cast<const v4f*>(ft + o.y + c0));
        r[si * 4 + 2] = __builtin_nontemporal_load(
            reinterpret_cast<const v4f*>(ft + o.z + c0));
        r[si * 4 + 3] = __builtin_nontemporal_load(
            reinterpret_cast<const v4f*>(ft + o.w + c0));
    }

    float acc[8];
    #pragma unroll
    for (int j = 0; j < 8; ++j) acc[j] = -FLT_MAX;

    #pragma unroll
    for (int si = 0; si < 4; ++si) {
        const float4 wv = s_w[f * 4 + si];
        const __half2* h00 = reinterpret_cast<const __half2*>(&r[si * 4 + 0]);
        const __half2* h10 = reinterpret_cast<const __half2*>(&r[si * 4 + 1]);
        const __half2* h01 = reinterpret_cast<const __half2*>(&r[si * 4 + 2]);
        const __half2* h11 = reinterpret_cast<const __half2*>(&r[si * 4 + 3]);
        #pragma unroll
        for (int k = 0; k < 4; ++k) {
            const float2 f00 = __half22float2(h00[k]);
            const float2 f10 = __half22float2(h10[k]);
            const float2 f01 = __half22float2(h01[k]);
            const float2 f11 = __half22float2(h11[k]);
            const float vx = f00.x * wv.x + f10.x * wv.y + f01.x * wv.z + f11.x * wv.w;
            const float vy = f00.y * wv.x + f10.y * wv.y + f01.y * wv.z + f11.y * wv.w;
            acc[2 * k]     = fmaxf(acc[2 * k],     vx);
            acc[2 * k + 1] = fmaxf(acc[2 * k + 1], vy);
        }
    }

    // Transpose (f, c) -> (c, f) through LDS; stride 9 => read-back is
    // conflict-free, write side only 2-way on 1/8 of traffic.
    #pragma unroll
    for (int j = 0; j < 8; ++j) o_tile[(c0 + j) * 9 + f] = acc[j];
    __syncthreads();

    float* op = out + (size_t)line * (C_DEPTH * N_FINAL) + t * N_FINAL;
    const float* row = &o_tile[t * 9];
    const v4f w0 = {row[0], row[1], row[2], row[3]};
    const v4f w1 = {row[4], row[5], row[6], row[7]};
    __builtin_nontemporal_store(w0, reinterpret_cast<v4f*>(op));
    __builtin_nontemporal_store(w1, reinterpret_cast<v4f*>(op) + 1);
}

extern "C" void kernel_launch(void* const* d_in, const int* in_sizes, int n_in,
                              void* d_out, int out_size, void* d_ws, size_t ws_size,
                              hipStream_t stream) {
    const float* feat  = (const float*)d_in[0];   // (128,128,128) fp32
    const float* lines = (const float*)d_in[1];   // (50000,4) fp32
    float* out = (float*)d_out;                   // (50000, 1024) fp32
    __half* ft = (__half*)d_ws;                   // 4 MB transposed fp16 features

    transpose_chw_hwc<<<NPIX / 64, 256, 0, stream>>>(feat, ft);
    line_pool<<<N_LINES, 128, 0, stream>>>(ft, lines, out);
}

// Round 4
// 278.682 us; speedup vs baseline: 1.2898x; 1.2898x over previous
//
#include <hip/hip_runtime.h>
#include <hip/hip_fp16.h>
#include <float.h>

#define C_DEPTH 128
#define H_DIM 128
#define W_DIM 128
#define NPIX (H_DIM * W_DIM)
#define N_SAMP 32
#define N_FINAL 8
#define N_LINES 50000

typedef float v4f __attribute__((ext_vector_type(4)));

// ---------------------------------------------------------------------------
// Pre-pass: transpose features (C,H,W) fp32 -> (H*W, C) fp16.
// ---------------------------------------------------------------------------
__global__ __launch_bounds__(256) void transpose_chw_hwc(
    const float* __restrict__ in, __half* __restrict__ out) {
    __shared__ float tile[64 * 130];
    const int p0 = blockIdx.x * 64;
    const int t = threadIdx.x;

    const int p_local = t & 63;
    const int cg = t >> 6;  // 0..3, each covers 32 channels
    #pragma unroll
    for (int i = 0; i < 32; ++i) {
        const int ch = cg * 32 + i;
        tile[p_local * 130 + ch] = in[ch * NPIX + p0 + p_local];
    }
    __syncthreads();

    const int cp = (t & 63) * 2;  // channel pair 0,2,...,126
    const int pg = t >> 6;        // 0..3, each covers 16 pixels
    #pragma unroll
    for (int i = 0; i < 16; ++i) {
        const int p = pg * 16 + i;
        const float2 f2 = *reinterpret_cast<const float2*>(&tile[p * 130 + cp]);
        *reinterpret_cast<__half2*>(&out[(size_t)(p0 + p) * C_DEPTH + cp]) =
            __floats2half2_rn(f2.x, f2.y);
    }
}

// sc0 load: bypass L1 ALLOCATE only (old glc semantics); L2 allocation kept
// (unlike nt, which is a TCC no-allocate and pushed the gather to L3 — round-3
// regression). Inline asm => compiler does NOT track vmcnt for these; an
// explicit s_waitcnt + sched_barrier is required before consuming results.
__device__ __forceinline__ v4f load_sc0(const __half* p) {
    v4f r;
    asm volatile("global_load_dwordx4 %0, %1, off sc0"
                 : "=v"(r) : "v"(p));
    return r;
}

// ---------------------------------------------------------------------------
// Main kernel: 1 block = 1 line, 128 threads = 8 pool-groups x 16 ch-groups.
//   f  = t >> 4 : pool group, consumes samples 4f..4f+3 (exact pool window)
//   tg = t & 15 : channel group, owns channels 8*tg .. 8*tg+7
// Coords/weights computed once by 32 threads into LDS (round-2 showed
// per-thread recompute costs +25us). All 16 gathers issued upfront with sc0.
// ---------------------------------------------------------------------------
__global__ __launch_bounds__(128) void line_pool(
    const __half* __restrict__ ft,      // (H*W, C) fp16 transposed features
    const float* __restrict__ lines,    // (N_LINES, 4)
    float* __restrict__ out) {
    __shared__ int4   s_off[N_SAMP];    // corner offsets in elements (x C)
    __shared__ float4 s_w[N_SAMP];      // bilinear weights (w00,w10,w01,w11)
    __shared__ float  o_tile[C_DEPTH * 9];

    const int line = blockIdx.x;
    const int t = threadIdx.x;

    if (t < N_SAMP) {
        const float4 l = reinterpret_cast<const float4*>(lines)[line];
        const float ts = (float)t / 31.0f;  // exact 1.0 at t=31
        const float px = l.x * ts + l.z * (1.0f - ts) - 0.5f;
        const float py = l.y * ts + l.w * (1.0f - ts) - 0.5f;
        // Reference: clamp AFTER floor, weights from the CLAMPED float coords.
        const float px0 = fminf(fmaxf(floorf(px), 0.0f), (float)(W_DIM - 1));
        const float py0 = fminf(fmaxf(floorf(py), 0.0f), (float)(H_DIM - 1));
        const float px1 = fminf(px0 + 1.0f, (float)(W_DIM - 1));
        const float py1 = fminf(py0 + 1.0f, (float)(H_DIM - 1));
        const int ix0 = (int)px0, iy0 = (int)py0;
        const int ix1 = (int)px1, iy1 = (int)py1;
        const float wx0 = px1 - px, wx1 = px - px0;
        const float wy0 = py1 - py, wy1 = py - py0;
        s_off[t] = make_int4((iy0 * W_DIM + ix0) * C_DEPTH,
                             (iy1 * W_DIM + ix0) * C_DEPTH,
                             (iy0 * W_DIM + ix1) * C_DEPTH,
                             (iy1 * W_DIM + ix1) * C_DEPTH);
        s_w[t] = make_float4(wy0 * wx0, wy1 * wx0, wy0 * wx1, wy1 * wx1);
    }
    __syncthreads();

    const int f  = t >> 4;
    const int tg = t & 15;
    const int c0 = tg * 8;
    const __half* fb = ft + c0;

    // Read all 4 samples' offsets/weights (normal LDS ops; compiler handles
    // lgkmcnt), then issue the 16 sc0 gathers back-to-back.
    int4   o[4];
    float4 w[4];
    #pragma unroll
    for (int si = 0; si < 4; ++si) {
        o[si] = s_off[f * 4 + si];
        w[si] = s_w[f * 4 + si];
    }

    v4f r[16];
    #pragma unroll
    for (int si = 0; si < 4; ++si) {
        r[si * 4 + 0] = load_sc0(fb + o[si].x);
        r[si * 4 + 1] = load_sc0(fb + o[si].y);
        r[si * 4 + 2] = load_sc0(fb + o[si].z);
        r[si * 4 + 3] = load_sc0(fb + o[si].w);
    }
    asm volatile("s_waitcnt vmcnt(0)" ::: "memory");
    __builtin_amdgcn_sched_barrier(0);  // rule #18: keep consumers below the wait

    float acc[8];
    #pragma unroll
    for (int j = 0; j < 8; ++j) acc[j] = -FLT_MAX;

    #pragma unroll
    for (int si = 0; si < 4; ++si) {
        const float4 wv = w[si];
        const __half2* h00 = reinterpret_cast<const __half2*>(&r[si * 4 + 0]);
        const __half2* h10 = reinterpret_cast<const __half2*>(&r[si * 4 + 1]);
        const __half2* h01 = reinterpret_cast<const __half2*>(&r[si * 4 + 2]);
        const __half2* h11 = reinterpret_cast<const __half2*>(&r[si * 4 + 3]);
        #pragma unroll
        for (int k = 0; k < 4; ++k) {
            const float2 f00 = __half22float2(h00[k]);
            const float2 f10 = __half22float2(h10[k]);
            const float2 f01 = __half22float2(h01[k]);
            const float2 f11 = __half22float2(h11[k]);
            const float vx = f00.x * wv.x + f10.x * wv.y + f01.x * wv.z + f11.x * wv.w;
            const float vy = f00.y * wv.x + f10.y * wv.y + f01.y * wv.z + f11.y * wv.w;
            acc[2 * k]     = fmaxf(acc[2 * k],     vx);
            acc[2 * k + 1] = fmaxf(acc[2 * k + 1], vy);
        }
    }

    // Transpose (f, c) -> (c, f) through LDS; stride 9 => read-back 2-way
    // (free), write side 4-way on a small op.
    #pragma unroll
    for (int j = 0; j < 8; ++j) o_tile[(c0 + j) * 9 + f] = acc[j];
    __syncthreads();

    float* op = out + (size_t)line * (C_DEPTH * N_FINAL) + t * N_FINAL;
    const float* row = &o_tile[t * 9];
    const v4f w0 = {row[0], row[1], row[2], row[3]};
    const v4f w1 = {row[4], row[5], row[6], row[7]};
    __builtin_nontemporal_store(w0, reinterpret_cast<v4f*>(op));
    __builtin_nontemporal_store(w1, reinterpret_cast<v4f*>(op) + 1);
}

extern "C" void kernel_launch(void* const* d_in, const int* in_sizes, int n_in,
                              void* d_out, int out_size, void* d_ws, size_t ws_size,
                              hipStream_t stream) {
    const float* feat  = (const float*)d_in[0];   // (128,128,128) fp32
    const float* lines = (const float*)d_in[1];   // (50000,4) fp32
    float* out = (float*)d_out;                   // (50000, 1024) fp32
    __half* ft = (__half*)d_ws;                   // 4 MB transposed fp16 features

    transpose_chw_hwc<<<NPIX / 64, 256, 0, stream>>>(feat, ft);
    line_pool<<<N_LINES, 128, 0, stream>>>(ft, lines, out);
}

// Round 5
// 277.017 us; speedup vs baseline: 1.2976x; 1.0060x over previous
//
#include <hip/hip_runtime.h>
#include <hip/hip_fp16.h>
#include <float.h>

#define C_DEPTH 128
#define H_DIM 128
#define W_DIM 128
#define NPIX (H_DIM * W_DIM)
#define N_SAMP 32
#define N_FINAL 8
#define N_LINES 50000

typedef float v4f __attribute__((ext_vector_type(4)));

// ---------------------------------------------------------------------------
// Pre-pass: transpose (C,H,W) fp32 -> (H*W, C) int8 with PER-PIXEL scale.
// Each pixel's 128-ch row is quantized by s = rowmax/127 (stored as fp16,
// and the quantization grid uses the fp16-ROUNDED scale so dequant is exact
// on the grid). Rows become 128 B = ONE cache line: halves the gather's
// line count, which R0-R4 evidence says is the service-rate bottleneck
// (~6.6 cyc/line/CU; model fit 137.5 vs ~138 us measured).
// ---------------------------------------------------------------------------
__global__ __launch_bounds__(256) void transpose_quant(
    const float* __restrict__ in, char* __restrict__ outq,
    __half* __restrict__ scale_out) {
    __shared__ float tile[64 * 130];
    __shared__ float s_part[4][64];
    __shared__ float s_inv[64];
    const int p0 = blockIdx.x * 64;
    const int t = threadIdx.x;

    const int p_local = t & 63;
    const int cg = t >> 6;  // 0..3, each covers 32 channels
    #pragma unroll
    for (int i = 0; i < 32; ++i) {
        const int ch = cg * 32 + i;
        tile[p_local * 130 + ch] = in[ch * NPIX + p0 + p_local];
    }
    __syncthreads();

    // per-pixel absmax over its 128 channels (4 partials x 32)
    float m = 0.0f;
    #pragma unroll
    for (int i = 0; i < 32; ++i)
        m = fmaxf(m, fabsf(tile[p_local * 130 + cg * 32 + i]));
    s_part[cg][p_local] = m;
    __syncthreads();
    if (t < 64) {
        float mm = fmaxf(fmaxf(s_part[0][t], s_part[1][t]),
                         fmaxf(s_part[2][t], s_part[3][t]));
        mm = fmaxf(mm, 1e-3f);
        const __half h = __float2half(mm * (1.0f / 127.0f));
        const float s_r = __half2float(h);   // the grid actually used
        scale_out[p0 + t] = h;
        s_inv[t] = 1.0f / s_r;
    }
    __syncthreads();

    const int cp = (t & 63) * 2;  // channel pair
    const int pg = t >> 6;        // 0..3, each covers 16 pixels
    #pragma unroll
    for (int i = 0; i < 16; ++i) {
        const int p = pg * 16 + i;
        const float inv = s_inv[p];
        const float2 f2 = *reinterpret_cast<const float2*>(&tile[p * 130 + cp]);
        const int q0 = (int)rintf(f2.x * inv);
        const int q1 = (int)rintf(f2.y * inv);
        const unsigned short pk =
            (unsigned short)((q0 & 0xff) | ((q1 & 0xff) << 8));
        *reinterpret_cast<unsigned short*>(
            outq + (size_t)(p0 + p) * C_DEPTH + cp) = pk;
    }
}

// sign-extend byte j (0..3) of a 32-bit word to float
__device__ __forceinline__ float sx(unsigned int w, int j) {
    return (float)((int)(w << ((3 - j) * 8)) >> 24);
}

// ---------------------------------------------------------------------------
// Main kernel: 1 block = 1 line, 128 threads = 8 pool-groups x 16 ch-groups.
//   f  = t >> 4 : pool group, consumes samples 4f..4f+3 (exact pool window)
//   tg = t & 15 : channel group, owns channels 8*tg .. 8*tg+7
// Setup (32 threads) computes corner BYTE offsets and bilinear weights with
// the per-pixel dequant scale FOLDED IN (weight_k *= scale[corner_k]), so the
// main loop is: load 8 int8 per corner (16-lane group = 128 B = 1 line),
// sext->fp32, weighted sum, running max. Plain loads (sc0/nt both regressed).
// ---------------------------------------------------------------------------
__global__ __launch_bounds__(128) void line_pool(
    const char* __restrict__ ft,        // (H*W, C) int8 features
    const __half* __restrict__ scale,   // (H*W) per-pixel scale, L1-resident
    const float* __restrict__ lines,    // (N_LINES, 4)
    float* __restrict__ out) {
    __shared__ int4   s_off[N_SAMP];    // corner offsets in BYTES (= pixel*128)
    __shared__ float4 s_w[N_SAMP];      // bilinear weights x dequant scale
    __shared__ float  o_tile[C_DEPTH * 9];

    const int line = blockIdx.x;
    const int t = threadIdx.x;

    if (t < N_SAMP) {
        const float4 l = reinterpret_cast<const float4*>(lines)[line];
        const float ts = (float)t / 31.0f;  // exact 1.0 at t=31
        const float px = l.x * ts + l.z * (1.0f - ts) - 0.5f;
        const float py = l.y * ts + l.w * (1.0f - ts) - 0.5f;
        // Reference: clamp AFTER floor, weights from the CLAMPED float coords.
        const float px0 = fminf(fmaxf(floorf(px), 0.0f), (float)(W_DIM - 1));
        const float py0 = fminf(fmaxf(floorf(py), 0.0f), (float)(H_DIM - 1));
        const float px1 = fminf(px0 + 1.0f, (float)(W_DIM - 1));
        const float py1 = fminf(py0 + 1.0f, (float)(H_DIM - 1));
        const int ix0 = (int)px0, iy0 = (int)py0;
        const int ix1 = (int)px1, iy1 = (int)py1;
        const float wx0 = px1 - px, wx1 = px - px0;
        const float wy0 = py1 - py, wy1 = py - py0;
        const int p00 = iy0 * W_DIM + ix0;
        const int p10 = iy1 * W_DIM + ix0;
        const int p01 = iy0 * W_DIM + ix1;
        const int p11 = iy1 * W_DIM + ix1;
        // fold per-pixel dequant scale into the bilinear weights
        const float s00 = __half2float(scale[p00]);
        const float s10 = __half2float(scale[p10]);
        const float s01 = __half2float(scale[p01]);
        const float s11 = __half2float(scale[p11]);
        s_off[t] = make_int4(p00 * C_DEPTH, p10 * C_DEPTH,
                             p01 * C_DEPTH, p11 * C_DEPTH);
        s_w[t] = make_float4(wy0 * wx0 * s00, wy1 * wx0 * s10,
                             wy0 * wx1 * s01, wy1 * wx1 * s11);
    }
    __syncthreads();

    const int f  = t >> 4;
    const int tg = t & 15;
    const int c0 = tg * 8;              // byte offset: 8 int8 channels

    float acc[8];
    #pragma unroll
    for (int j = 0; j < 8; ++j) acc[j] = -FLT_MAX;

    #pragma unroll
    for (int si = 0; si < 4; ++si) {
        const int4   o  = s_off[f * 4 + si];
        const float4 wv = s_w[f * 4 + si];
        const uint2 d00 = *reinterpret_cast<const uint2*>(ft + o.x + c0);
        const uint2 d10 = *reinterpret_cast<const uint2*>(ft + o.y + c0);
        const uint2 d01 = *reinterpret_cast<const uint2*>(ft + o.z + c0);
        const uint2 d11 = *reinterpret_cast<const uint2*>(ft + o.w + c0);
        #pragma unroll
        for (int j = 0; j < 8; ++j) {
            const int jj = j & 3;
            const unsigned int w00 = (j < 4) ? d00.x : d00.y;
            const unsigned int w10 = (j < 4) ? d10.x : d10.y;
            const unsigned int w01 = (j < 4) ? d01.x : d01.y;
            const unsigned int w11 = (j < 4) ? d11.x : d11.y;
            const float v = sx(w00, jj) * wv.x + sx(w10, jj) * wv.y
                          + sx(w01, jj) * wv.z + sx(w11, jj) * wv.w;
            acc[j] = fmaxf(acc[j], v);
        }
    }

    // Transpose (f, c) -> (c, f) through LDS; stride 9 => read-back 2-way
    // (free), write side 4-way on a small op.
    #pragma unroll
    for (int j = 0; j < 8; ++j) o_tile[(c0 + j) * 9 + f] = acc[j];
    __syncthreads();

    float* op = out + (size_t)line * (C_DEPTH * N_FINAL) + t * N_FINAL;
    const float* row = &o_tile[t * 9];
    const v4f w0 = {row[0], row[1], row[2], row[3]};
    const v4f w1 = {row[4], row[5], row[6], row[7]};
    __builtin_nontemporal_store(w0, reinterpret_cast<v4f*>(op));
    __builtin_nontemporal_store(w1, reinterpret_cast<v4f*>(op) + 1);
}

extern "C" void kernel_launch(void* const* d_in, const int* in_sizes, int n_in,
                              void* d_out, int out_size, void* d_ws, size_t ws_size,
                              hipStream_t stream) {
    const float* feat  = (const float*)d_in[0];   // (128,128,128) fp32
    const float* lines = (const float*)d_in[1];   // (50000,4) fp32
    float* out = (float*)d_out;                   // (50000, 1024) fp32
    char*   ft = (char*)d_ws;                     // 2 MB int8 features
    __half* sc = (__half*)((char*)d_ws + (size_t)NPIX * C_DEPTH);  // 32 KB scales

    transpose_quant<<<NPIX / 64, 256, 0, stream>>>(feat, ft, sc);
    line_pool<<<N_LINES, 128, 0, stream>>>(ft, sc, lines, out);
}

// Round 6
// 244.146 us; speedup vs baseline: 1.4723x; 1.1346x over previous
//
#include <hip/hip_runtime.h>
#include <hip/hip_fp16.h>
#include <float.h>

#define C_DEPTH 128
#define H_DIM 128
#define W_DIM 128
#define NPIX (H_DIM * W_DIM)
#define N_SAMP 32
#define N_FINAL 8
#define N_LINES 50000

typedef float v4f __attribute__((ext_vector_type(4)));

// ---------------------------------------------------------------------------
// Pre-pass: transpose (C,H,W) fp32 -> (H*W, C) int8 with PER-PIXEL scale
// (fp16-rounded scale so dequant is exact on the grid). Also zeroes a 128-B
// pad row after the map: x-pair chunk loads at (ix0==W-1, iy==H-1) read
// 128 B past the map; weight there is folded to 0, and 0 x 0 = 0 (no NaN).
// ---------------------------------------------------------------------------
__global__ __launch_bounds__(256) void transpose_quant(
    const float* __restrict__ in, char* __restrict__ outq,
    __half* __restrict__ scale_out) {
    __shared__ float tile[64 * 130];
    __shared__ float s_part[4][64];
    __shared__ float s_inv[64];
    const int p0 = blockIdx.x * 64;
    const int t = threadIdx.x;

    if (blockIdx.x == 0 && t < 32)
        *reinterpret_cast<int*>(outq + (size_t)NPIX * C_DEPTH + t * 4) = 0;

    const int p_local = t & 63;
    const int cg = t >> 6;  // 0..3, each covers 32 channels
    #pragma unroll
    for (int i = 0; i < 32; ++i) {
        const int ch = cg * 32 + i;
        tile[p_local * 130 + ch] = in[ch * NPIX + p0 + p_local];
    }
    __syncthreads();

    float m = 0.0f;
    #pragma unroll
    for (int i = 0; i < 32; ++i)
        m = fmaxf(m, fabsf(tile[p_local * 130 + cg * 32 + i]));
    s_part[cg][p_local] = m;
    __syncthreads();
    if (t < 64) {
        float mm = fmaxf(fmaxf(s_part[0][t], s_part[1][t]),
                         fmaxf(s_part[2][t], s_part[3][t]));
        mm = fmaxf(mm, 1e-3f);
        const __half h = __float2half(mm * (1.0f / 127.0f));
        const float s_r = __half2float(h);   // the grid actually used
        scale_out[p0 + t] = h;
        s_inv[t] = 1.0f / s_r;
    }
    __syncthreads();

    const int cp = (t & 63) * 2;
    const int pg = t >> 6;
    #pragma unroll
    for (int i = 0; i < 16; ++i) {
        const int p = pg * 16 + i;
        const float inv = s_inv[p];
        const float2 f2 = *reinterpret_cast<const float2*>(&tile[p * 130 + cp]);
        const int q0 = (int)rintf(f2.x * inv);
        const int q1 = (int)rintf(f2.y * inv);
        const unsigned short pk =
            (unsigned short)((q0 & 0xff) | ((q1 & 0xff) << 8));
        *reinterpret_cast<unsigned short*>(
            outq + (size_t)(p0 + p) * C_DEPTH + cp) = pk;
    }
}

// sign-extend byte j (0..3) of a 32-bit word to float
__device__ __forceinline__ float sx(unsigned int w, int j) {
    return (float)((int)(w << ((3 - j) * 8)) >> 24);
}

// ---------------------------------------------------------------------------
// Main kernel: 1 block = 1 line, 128 threads = 8 pool-groups x 16 ch-octets.
// Request-count-halved gather: per si, each WAVE loads its 4 samples' full
// bilinear neighborhoods as 8 x-pair chunks (256 B each, x0|x1 rows adjacent
// in int8 layout) using TWO dwordx4 instructions (8 TA phases) instead of
// eight (16 phases). Lanes then redistribute channels through a per-wave LDS
// stage (in-order DS pipe within a wave; explicit lgkmcnt+sched_barrier).
//   load:  fl = lane>>4 selects sample (f = w*4+fl), slot = lane&15 is the
//          16-B slot in the 256-B chunk; d0 = y0-pair, d1 = y1-pair.
//   read:  same lane's octet tg (= slot) pulls its 8 channels of all 4
//          corners from its own f's chunks. Bank-uniform by construction.
// o_tile is UNIONed onto the stage (barrier-separated) -> 16 blocks/CU.
// ---------------------------------------------------------------------------
__global__ __launch_bounds__(128) void line_pool(
    const char* __restrict__ ft,        // (H*W, C) int8 + 128-B zero pad
    const __half* __restrict__ scale,   // (H*W) per-pixel scale
    const float* __restrict__ lines,    // (N_LINES, 4)
    float* __restrict__ out) {
    __shared__ __align__(16) char stage[2 * 2 * 4 * 512]; // [wave][buf][fl][512]
    __shared__ int2   s_pb[N_SAMP];     // byte offs of (y0,x0-pair),(y1,x0-pair)
    __shared__ float4 s_w[N_SAMP];      // bilinear weights x dequant scale
    float* o_tile = reinterpret_cast<float*>(stage);  // 4608 B <= 8192 B union

    const int line = blockIdx.x;
    const int t = threadIdx.x;

    if (t < N_SAMP) {
        const float4 l = reinterpret_cast<const float4*>(lines)[line];
        const float ts = (float)t / 31.0f;  // exact 1.0 at t=31
        const float px = l.x * ts + l.z * (1.0f - ts) - 0.5f;
        const float py = l.y * ts + l.w * (1.0f - ts) - 0.5f;
        // Reference: clamp AFTER floor, weights from the CLAMPED float coords.
        const float px0 = fminf(fmaxf(floorf(px), 0.0f), (float)(W_DIM - 1));
        const float py0 = fminf(fmaxf(floorf(py), 0.0f), (float)(H_DIM - 1));
        const float px1 = fminf(px0 + 1.0f, (float)(W_DIM - 1));
        const float py1 = fminf(py0 + 1.0f, (float)(H_DIM - 1));
        const int ix0 = (int)px0, iy0 = (int)py0;
        const int ix1 = (int)px1, iy1 = (int)py1;
        const float wx0 = px1 - px, wx1 = px - px0;
        const float wy0 = py1 - py, wy1 = py - py0;
        const int p00 = iy0 * W_DIM + ix0;
        const int p10 = iy1 * W_DIM + ix0;
        const int p01 = iy0 * W_DIM + ix1;
        const int p11 = iy1 * W_DIM + ix1;
        const float s00 = __half2float(scale[p00]);
        const float s10 = __half2float(scale[p10]);
        const float s01 = __half2float(scale[p01]);
        const float s11 = __half2float(scale[p11]);
        float4 wv = make_float4(wy0 * wx0 * s00, wy1 * wx0 * s10,
                                wy0 * wx1 * s01, wy1 * wx1 * s11);
        // Right-edge clamp: x1==x0 -> same pixel, same scale -> exact fold.
        // The chunk's second 128 B is then unused (weight 0; pad row is 0).
        if (ix1 == ix0) { wv.x += wv.z; wv.z = 0.0f; wv.y += wv.w; wv.w = 0.0f; }
        s_pb[t] = make_int2(p00 * C_DEPTH, p10 * C_DEPTH);
        s_w[t] = wv;
    }
    __syncthreads();

    const int w    = t >> 6;            // wave in block
    const int lane = t & 63;
    const int fl   = lane >> 4;         // f within wave = chunk group served
    const int slot = lane & 15;         // 16-B slot in chunk; also ch-octet tg
    const int f    = t >> 4;            // global pool group 0..7

    char* wbase = stage + (w * 4096 + fl * 512);

    float acc[8];
    #pragma unroll
    for (int j = 0; j < 8; ++j) acc[j] = -FLT_MAX;

    #pragma unroll
    for (int si = 0; si < 4; ++si) {
        const int smp = f * 4 + si;
        const int2 pb = s_pb[smp];
        const v4f d0 = *reinterpret_cast<const v4f*>(ft + pb.x + slot * 16);
        const v4f d1 = *reinterpret_cast<const v4f*>(ft + pb.y + slot * 16);
        char* bp = wbase + (si & 1) * 2048;   // double-buffered per wave
        *reinterpret_cast<v4f*>(bp + slot * 16)       = d0;  // y0: x0|x1
        *reinterpret_cast<v4f*>(bp + 256 + slot * 16) = d1;  // y1: x0|x1
        // Cross-lane LDS handoff within the wave: drain DS, pin order.
        asm volatile("s_waitcnt lgkmcnt(0)" ::: "memory");
        __builtin_amdgcn_sched_barrier(0);

        const float4 wv = s_w[smp];
        const uint2 d00 = *reinterpret_cast<const uint2*>(bp +       slot * 8);
        const uint2 d01 = *reinterpret_cast<const uint2*>(bp + 128 + slot * 8);
        const uint2 d10 = *reinterpret_cast<const uint2*>(bp + 256 + slot * 8);
        const uint2 d11 = *reinterpret_cast<const uint2*>(bp + 384 + slot * 8);
        #pragma unroll
        for (int j = 0; j < 8; ++j) {
            const int jj = j & 3;
            const unsigned int b00 = (j < 4) ? d00.x : d00.y;
            const unsigned int b01 = (j < 4) ? d01.x : d01.y;
            const unsigned int b10 = (j < 4) ? d10.x : d10.y;
            const unsigned int b11 = (j < 4) ? d11.x : d11.y;
            const float v = sx(b00, jj) * wv.x + sx(b10, jj) * wv.y
                          + sx(b01, jj) * wv.z + sx(b11, jj) * wv.w;
            acc[j] = fmaxf(acc[j], v);
        }
    }

    __syncthreads();   // stage memory is reused as o_tile below

    const int c0 = slot * 8;
    #pragma unroll
    for (int j = 0; j < 8; ++j) o_tile[(c0 + j) * 9 + f] = acc[j];
    __syncthreads();

    float* op = out + (size_t)line * (C_DEPTH * N_FINAL) + t * N_FINAL;
    const float* row = &o_tile[t * 9];
    const v4f w0 = {row[0], row[1], row[2], row[3]};
    const v4f w1 = {row[4], row[5], row[6], row[7]};
    __builtin_nontemporal_store(w0, reinterpret_cast<v4f*>(op));
    __builtin_nontemporal_store(w1, reinterpret_cast<v4f*>(op) + 1);
}

extern "C" void kernel_launch(void* const* d_in, const int* in_sizes, int n_in,
                              void* d_out, int out_size, void* d_ws, size_t ws_size,
                              hipStream_t stream) {
    const float* feat  = (const float*)d_in[0];   // (128,128,128) fp32
    const float* lines = (const float*)d_in[1];   // (50000,4) fp32
    float* out = (float*)d_out;                   // (50000, 1024) fp32
    char*   ft = (char*)d_ws;                     // 2 MB int8 map + 128 B pad
    __half* sc = (__half*)((char*)d_ws + (size_t)NPIX * C_DEPTH + 256);

    transpose_quant<<<NPIX / 64, 256, 0, stream>>>(feat, ft, sc);
    line_pool<<<N_LINES, 128, 0, stream>>>(ft, sc, lines, out);
}